// Round 8
// baseline (53.890 us; speedup 1.0000x reference)
//
#include <hip/hip_runtime.h>

#define NB   4096
#define NBLK 256
#define NJ   16      // b's per block (NBLK*NJ == NB)

typedef __attribute__((ext_vector_type(4))) float f32x4;
typedef __attribute__((ext_vector_type(8))) short short8;
typedef __attribute__((ext_vector_type(4))) int   int4v;
typedef __attribute__((ext_vector_type(2))) int   int2v;

union Frag { int4v i; short8 s; };

__device__ __forceinline__ unsigned short f2bf(float f) {
  unsigned int u = __float_as_uint(f);
  u = (u + 0x7FFFu + ((u >> 16) & 1u)) >> 16;
  return (unsigned short)u;
}

__device__ __forceinline__ int cvtpk(float lo, float hi) {
  int r;
  asm("v_cvt_pk_bf16_f32 %0, %1, %2" : "=v"(r) : "v"(lo), "v"(hi));
  return r;
}

// ---------------------------------------------------------------------------
// Pre-kernel: conv_w f32 [o=128][i=128][k=2] -> bf16 B-fragments in d_ws.
// Fragment f = ((kk*2 + ker)*8 + ng); lane l holds 8 bf16:
//   col = ng*16 + (l&15),  k = kk*32 + (l>>4)*8 + j (j=0..7)
// at ws + f*1024B + l*16B.   (validated R1-R6)
// ---------------------------------------------------------------------------
__global__ __launch_bounds__(512)
void wconv_kernel(const float* __restrict__ conv_w, unsigned short* __restrict__ ws)
{
  int flat = blockIdx.x * 512 + threadIdx.x;   // 0..4095
  int lane = flat & 63;
  int ng   = (flat >> 6) & 7;
  int ker  = (flat >> 9) & 1;
  int kk   = flat >> 10;
  int col  = ng * 16 + (lane & 15);
  int k0   = kk * 32 + (lane >> 4) * 8;
  short8 s;
#pragma unroll
  for (int j = 0; j < 8; ++j)
    s[j] = (short)f2bf(conv_w[col * 256 + (k0 + j) * 2 + ker]);
  *(short8*)(ws + (size_t)flat * 8) = s;
}

// ---------------------------------------------------------------------------
// Main kernel. Shifted-K conv: C[r] = A[r]*W0 + A[r+1]*W1 as one K=256 GEMM
// (A[r+1] frags = +1-row LDS reads; rows r%8==7 masked; row 128 = junk, masked).
// Depth-3 register gather pipeline, single LDS A buffer.
// LDS: A bf16 [129][272B] [0,35088) ; RED f32 [2][128] [35088,36112).
// ---------------------------------------------------------------------------
#define RED_OFF 35088
#define LDS_BYTES 36112
#define A_STRIDE 272

__global__ __launch_bounds__(512)
void path_emb_kernel(const int* __restrict__ path_input,
                     const int* __restrict__ path_type,
                     const float* __restrict__ t0, const float* __restrict__ t1,
                     const float* __restrict__ t2, const float* __restrict__ t3,
                     const unsigned short* __restrict__ wfrag,
                     const float* __restrict__ conv_b,
                     float* __restrict__ out)
{
  __shared__ __align__(16) char lds[LDS_BYTES];
  const int blk  = blockIdx.x;
  const int tid  = threadIdx.x;
  const int wid  = tid >> 6;
  const int lane = tid & 63;
  const int lrow = lane & 15;
  const int lk   = lane >> 4;
  const int R = wid & 1;      // row half (64 rows)
  const int C = wid >> 1;     // col quarter (32 cols)

  const int* idxg = path_input + (size_t)blk * NJ * 128;
  float cb = (tid < 128) ? conv_b[tid] : 0.0f;

  // Gather assignment (thread-fixed): 4 threads per row, 128 B each.
  const int grow = tid >> 2;
  const int gq   = tid & 3;
  const int ty   = path_type[grow & 7];
  const float* tb = (ty == 0) ? t0 : (ty == 1) ? t1 : (ty == 2) ? t2 : t3;

  // ---- W fragments resident in registers: wreg[kk][ker][n]
  Frag wreg[4][2][2];
#pragma unroll
  for (int kk = 0; kk < 4; ++kk)
#pragma unroll
    for (int ker = 0; ker < 2; ++ker)
#pragma unroll
      for (int n = 0; n < 2; ++n) {
        int f = (kk * 2 + ker) * 8 + C * 2 + n;
        wreg[kk][ker][n].i = *(const int4v*)(wfrag + (size_t)f * 512 + lane * 8);
      }

  auto ISSUE = [&](int j, f32x4 (&ld)[8]) {
    int idx = idxg[j * 128 + grow];
    const float* g = tb + (size_t)idx * 128 + gq * 4;
#pragma unroll
    for (int i = 0; i < 8; ++i) ld[i] = *(const f32x4*)(g + i * 16);
  };
  auto WRITE = [&](const f32x4 (&ld)[8]) {
    char* dst = lds + grow * A_STRIDE + gq * 8;
#pragma unroll
    for (int i = 0; i < 8; ++i) {
      int2v w;
      w[0] = cvtpk(ld[i][0], ld[i][1]);
      w[1] = cvtpk(ld[i][2], ld[i][3]);
      *(int2v*)(dst + i * 32) = w;
    }
  };

  float* red = (float*)(lds + RED_OFF);
  const int arow0 = R * 64 + lrow;

  auto COMPUTE = [&]() {
    f32x4 acc[4][2] = {};
#pragma unroll
    for (int kk = 0; kk < 4; ++kk) {
      Frag alo[4], ahi[4];
#pragma unroll
      for (int m = 0; m < 4; ++m) {
        const char* p = lds + (arow0 + m * 16) * A_STRIDE + kk * 64 + lk * 16;
        alo[m].i = *(const int4v*)(p);
        ahi[m].i = *(const int4v*)(p + A_STRIDE);   // row+1 (shifted tap)
      }
#pragma unroll
      for (int m = 0; m < 4; ++m)
#pragma unroll
        for (int n = 0; n < 2; ++n) {
          acc[m][n] = __builtin_amdgcn_mfma_f32_16x16x32_bf16(
              alo[m].s, wreg[kk][0][n].s, acc[m][n], 0, 0, 0);
          acc[m][n] = __builtin_amdgcn_mfma_f32_16x16x32_bf16(
              ahi[m].s, wreg[kk][1][n].s, acc[m][n], 0, 0, 0);
        }
    }
    float vmax[2] = {-1e30f, -1e30f};
#pragma unroll
    for (int m = 0; m < 4; ++m)
#pragma unroll
      for (int n = 0; n < 2; ++n)
#pragma unroll
        for (int r = 0; r < 4; ++r) {
          int rloc = lk * 4 + r;
          if ((rloc & 7) == 7) continue;     // t==7: no window (masks junk too)
          vmax[n] = fmaxf(vmax[n], acc[m][n][r]);
        }
#pragma unroll
    for (int n = 0; n < 2; ++n) {
      float v = vmax[n];
      v = fmaxf(v, __shfl_xor(v, 16));
      v = fmaxf(v, __shfl_xor(v, 32));
      vmax[n] = v;
    }
    if (lane < 16) {
#pragma unroll
      for (int n = 0; n < 2; ++n)
        red[R * 128 + C * 32 + n * 16 + lane] = vmax[n];
    }
  };

  // lgkm-only barrier: LDS ordered; global loads/stores stay in flight
  auto BAR = [&]() {
    asm volatile("s_waitcnt lgkmcnt(0)" ::: "memory");
    __builtin_amdgcn_sched_barrier(0);
    __builtin_amdgcn_s_barrier();
    __builtin_amdgcn_sched_barrier(0);
  };

  // ---- depth-3 pipeline: batch k lives in buf[k%3]
  f32x4 lA[8], lB[8], lC[8];
  ISSUE(0, lA);
  ISSUE(1, lB);
  ISSUE(2, lC);
  WRITE(lA);                     // waits batch 0 only (compiler-counted vmcnt)
  BAR();

#pragma unroll
  for (int j = 0; j < NJ; ++j) {
    if (j + 3 < NJ) {            // issue batch j+3 into freed buffer (j%3)
      if (j % 3 == 0)      ISSUE(j + 3, lA);
      else if (j % 3 == 1) ISSUE(j + 3, lB);
      else                 ISSUE(j + 3, lC);
    }
    __builtin_amdgcn_sched_barrier(0);

    COMPUTE();                   // batch j from LDS -> red
    BAR();                       // red visible; A fully consumed

    if (tid < 128)               // fire-and-forget store
      out[(size_t)(blk * NJ + j) * 128 + tid] =
          fmaxf(red[tid], red[128 + tid]) + cb;

    if (j + 1 < NJ) {            // stage batch j+1 (2-iteration lead)
      if ((j + 1) % 3 == 0)      WRITE(lA);
      else if ((j + 1) % 3 == 1) WRITE(lB);
      else                       WRITE(lC);
    }
    BAR();                       // new A visible; red consumed
  }
}

extern "C" void kernel_launch(void* const* d_in, const int* in_sizes, int n_in,
                              void* d_out, int out_size, void* d_ws, size_t ws_size,
                              hipStream_t stream) {
  const int*   path_input = (const int*)d_in[0];
  const int*   path_type  = (const int*)d_in[3];
  const float* user_emb   = (const float*)d_in[4];
  const float* item_emb   = (const float*)d_in[5];
  const float* ca_emb     = (const float*)d_in[6];
  const float* ci_emb     = (const float*)d_in[7];
  const float* conv_w     = (const float*)d_in[8];
  const float* conv_b     = (const float*)d_in[9];
  float* out = (float*)d_out;
  unsigned short* wfrag = (unsigned short*)d_ws;   // 64 KB bf16 fragment buffer

  wconv_kernel<<<dim3(8), dim3(512), 0, stream>>>(conv_w, wfrag);
  path_emb_kernel<<<dim3(NBLK), dim3(512), 0, stream>>>(
      path_input, path_type, user_emb, item_emb, ca_emb, ci_emb,
      wfrag, conv_b, out);
}

// Round 9
// 50.945 us; speedup vs baseline: 1.0578x; 1.0578x over previous
//
#include <hip/hip_runtime.h>

#define NBLK 2048   // blocks; each handles 2 b's (4 half-jobs)

typedef __attribute__((ext_vector_type(4))) float f32x4;
typedef __attribute__((ext_vector_type(8))) short short8;
typedef __attribute__((ext_vector_type(4))) int   int4v;
typedef __attribute__((ext_vector_type(2))) int   int2v;

union Frag { int4v i; short8 s; };

__device__ __forceinline__ unsigned short f2bf(float f) {
  unsigned int u = __float_as_uint(f);
  u = (u + 0x7FFFu + ((u >> 16) & 1u)) >> 16;
  return (unsigned short)u;
}

__device__ __forceinline__ int cvtpk(float lo, float hi) {
  int r;
  asm("v_cvt_pk_bf16_f32 %0, %1, %2" : "=v"(r) : "v"(lo), "v"(hi));
  return r;
}

// ---------------------------------------------------------------------------
// Pre-kernel: conv_w f32 [o=128][i=128][k=2] -> bf16 B-fragments in d_ws.
// Fragment f = ((kk*2 + ker)*8 + ng); lane l holds 8 bf16:
//   col = ng*16 + (l&15),  k = kk*32 + (l>>4)*8 + j (j=0..7)
// at ws + f*1024B + l*16B.   (validated R1-R7)
// ---------------------------------------------------------------------------
__global__ __launch_bounds__(512)
void wconv_kernel(const float* __restrict__ conv_w, unsigned short* __restrict__ ws)
{
  int flat = blockIdx.x * 512 + threadIdx.x;   // 0..4095
  int lane = flat & 63;
  int ng   = (flat >> 6) & 7;
  int ker  = (flat >> 9) & 1;
  int kk   = flat >> 10;
  int col  = ng * 16 + (lane & 15);
  int k0   = kk * 32 + (lane >> 4) * 8;
  short8 s;
#pragma unroll
  for (int j = 0; j < 8; ++j)
    s[j] = (short)f2bf(conv_w[col * 256 + (k0 + j) * 2 + ker]);
  *(short8*)(ws + (size_t)flat * 8) = s;
}

// ---------------------------------------------------------------------------
// Main kernel. Block = 256 thr = 4 waves; job = (b, half) = 64 rows (8 p's).
// Windows never cross the half boundary (row 63 is t=7, masked), so halves
// are independent; running col-max lives in registers across a b's 2 jobs.
// Wave C owns cols [C*32, C*32+32): wreg = 64 VGPR. Per-job m-loop streams
// acc (8 regs). LDS: two bf16 A-buffers [65][272B] (row 64 = junk pad for
// the +1-row shifted-tap read; only masked rows consume it).
// Target: <=128 total regs -> 4 waves/SIMD; 34.5 KB LDS -> 4 blocks/CU.
// ---------------------------------------------------------------------------
#define A_STRIDE 272
#define ABUF     (65 * A_STRIDE)       // 17680 B
#define LDS_BYTES (2 * ABUF)           // 35360 B

__global__ __launch_bounds__(256)
void path_emb_kernel(const int* __restrict__ path_input,
                     const int* __restrict__ path_type,
                     const float* __restrict__ t0, const float* __restrict__ t1,
                     const float* __restrict__ t2, const float* __restrict__ t3,
                     const unsigned short* __restrict__ wfrag,
                     const float* __restrict__ conv_b,
                     float* __restrict__ out)
{
  __shared__ __align__(16) char lds[LDS_BYTES];
  const int blk  = blockIdx.x;
  const int tid  = threadIdx.x;
  const int C    = tid >> 6;        // wave id = col quarter (32 cols)
  const int lane = tid & 63;
  const int lrow = lane & 15;
  const int g    = lane >> 4;       // k-group / row-subgroup

  // ---- gather role: 4 threads per row, 64 rows per job
  const int grow = tid >> 2;        // row within half (0..63)
  const int gq   = tid & 3;
  {
  }
  const int ty   = path_type[grow & 7];
  const float* tb = (ty == 0) ? t0 : (ty == 1) ? t1 : (ty == 2) ? t2 : t3;

  // indices for all 4 jobs (b = blk*2 + (jb>>1), half = jb&1)
  int idx[4];
#pragma unroll
  for (int jb = 0; jb < 4; ++jb)
    idx[jb] = path_input[((size_t)blk * 2 + (jb >> 1)) * 128 + (jb & 1) * 64 + grow];

  // bias for my cols
  float cb[2];
#pragma unroll
  for (int n = 0; n < 2; ++n) cb[n] = conv_b[C * 32 + n * 16 + lrow];

  // ---- W fragments resident in VGPRs (64 regs)
  Frag wreg[4][2][2];   // [kk][ker][n]
#pragma unroll
  for (int kk = 0; kk < 4; ++kk)
#pragma unroll
    for (int ker = 0; ker < 2; ++ker)
#pragma unroll
      for (int n = 0; n < 2; ++n) {
        int f = (kk * 2 + ker) * 8 + C * 2 + n;
        wreg[kk][ker][n].i = *(const int4v*)(wfrag + (size_t)f * 512 + lane * 8);
      }

  f32x4 ld[8];
  auto ISSUE = [&](int jb) {
    const float* base = tb + (size_t)idx[jb] * 128 + gq * 4;
#pragma unroll
    for (int i = 0; i < 8; ++i) ld[i] = *(const f32x4*)(base + i * 16);
  };
  auto WRITE = [&](int buf) {
    char* dst = lds + buf * ABUF + grow * A_STRIDE + gq * 8;
#pragma unroll
    for (int i = 0; i < 8; ++i) {
      int2v w;
      w[0] = cvtpk(ld[i][0], ld[i][1]);
      w[1] = cvtpk(ld[i][2], ld[i][3]);
      *(int2v*)(dst + i * 32) = w;
    }
  };

  float vmax[2] = {-1e30f, -1e30f};

  auto COMPUTE = [&](int buf) {
    const char* Ab = lds + buf * ABUF;
#pragma unroll
    for (int m = 0; m < 4; ++m) {
      f32x4 acc[2] = {};
#pragma unroll
      for (int kk = 0; kk < 4; ++kk) {
        Frag alo, ahi;
        const char* p = Ab + (m * 16 + lrow) * A_STRIDE + kk * 64 + g * 16;
        alo.i = *(const int4v*)(p);
        ahi.i = *(const int4v*)(p + A_STRIDE);      // row+1 (shifted tap)
        acc[0] = __builtin_amdgcn_mfma_f32_16x16x32_bf16(alo.s, wreg[kk][0][0].s, acc[0], 0, 0, 0);
        acc[1] = __builtin_amdgcn_mfma_f32_16x16x32_bf16(alo.s, wreg[kk][0][1].s, acc[1], 0, 0, 0);
        acc[0] = __builtin_amdgcn_mfma_f32_16x16x32_bf16(ahi.s, wreg[kk][1][0].s, acc[0], 0, 0, 0);
        acc[1] = __builtin_amdgcn_mfma_f32_16x16x32_bf16(ahi.s, wreg[kk][1][1].s, acc[1], 0, 0, 0);
      }
#pragma unroll
      for (int n = 0; n < 2; ++n)
#pragma unroll
        for (int r = 0; r < 4; ++r) {
          int rloc = g * 4 + r;              // row within 16-row fragment
          if ((rloc & 7) == 7) continue;     // t==7: no window (masks pad too)
          vmax[n] = fmaxf(vmax[n], acc[n][r]);
        }
    }
  };

  // lgkm-only barrier: LDS ordered; global loads/stores stay in flight
  auto BAR = [&]() {
    asm volatile("s_waitcnt lgkmcnt(0)" ::: "memory");
    __builtin_amdgcn_sched_barrier(0);
    __builtin_amdgcn_s_barrier();
    __builtin_amdgcn_sched_barrier(0);
  };

  // ---- prologue: stage job 0
  ISSUE(0);
  WRITE(0);
  BAR();

  // ---- 4 jobs: compute buf jb&1, prefetch jb+1 across the compute
#pragma unroll
  for (int jb = 0; jb < 4; ++jb) {
    if (jb + 1 < 4) ISSUE(jb + 1);
    __builtin_amdgcn_sched_barrier(0);

    COMPUTE(jb & 1);

    if (jb & 1) {   // b's second half done -> reduce + store, reset
#pragma unroll
      for (int n = 0; n < 2; ++n) {
        float v = vmax[n];
        v = fmaxf(v, __shfl_xor(v, 16));
        v = fmaxf(v, __shfl_xor(v, 32));
        vmax[n] = v;
      }
      if (lane < 16) {
        int b = blk * 2 + (jb >> 1);
#pragma unroll
        for (int n = 0; n < 2; ++n)
          out[(size_t)b * 128 + C * 32 + n * 16 + lrow] = vmax[n] + cb[n];
      }
      vmax[0] = -1e30f; vmax[1] = -1e30f;
    }

    if (jb + 1 < 4) WRITE((jb + 1) & 1);
    BAR();
  }
}

extern "C" void kernel_launch(void* const* d_in, const int* in_sizes, int n_in,
                              void* d_out, int out_size, void* d_ws, size_t ws_size,
                              hipStream_t stream) {
  const int*   path_input = (const int*)d_in[0];
  const int*   path_type  = (const int*)d_in[3];
  const float* user_emb   = (const float*)d_in[4];
  const float* item_emb   = (const float*)d_in[5];
  const float* ca_emb     = (const float*)d_in[6];
  const float* ci_emb     = (const float*)d_in[7];
  const float* conv_w     = (const float*)d_in[8];
  const float* conv_b     = (const float*)d_in[9];
  float* out = (float*)d_out;
  unsigned short* wfrag = (unsigned short*)d_ws;   // 64 KB bf16 fragment buffer

  wconv_kernel<<<dim3(8), dim3(512), 0, stream>>>(conv_w, wfrag);
  path_emb_kernel<<<dim3(NBLK), dim3(256), 0, stream>>>(
      path_input, path_type, user_emb, item_emb, ca_emb, ci_emb,
      wfrag, conv_b, out);
}